// Round 3
// baseline (111.504 us; speedup 1.0000x reference)
//
#include <hip/hip_runtime.h>
#include <hip/hip_bf16.h>

// Problem constants (from reference)
#define Bg 64       // graphs
#define Nn 256      // nodes per subgraph
#define Ee 2048     // edges per subgraph
#define Dd 128      // hidden dim
#define Hh 4        // heads
#define MAXJ 40     // cap on in-edges of node 0 (+self) per layer; Binom(2048,1/256): P(>38)~1e-17
#define RS 132      // LDS row stride (128 + 4 pad)
#define MAGIC 0x9E3779B1u   // flag value; workspace poison fill will never equal this

__device__ __forceinline__ float bf2f(unsigned short u) {
    return __uint_as_float(((unsigned)u) << 16);
}

// ---------------------------------------------------------------------------
// One fused kernel, 72 blocks x 512 threads:
//   blocks 0..7   = PRODUCERS: block x=(l,h) folds {att_src, att_dst, mlp
//                   half} through W_l[h] (W read ONCE chip-wide, coalesced),
//                   writes 3 wv rows + bdot to global, release-fence, sets
//                   flag[x]=MAGIC via device-scope atomic.
//   blocks 8..71  = CONSUMERS: one per graph. All wv-independent work (adj
//                   scan -> gid -> emb gather, ~cold-HBM latency chain) runs
//                   CONCURRENTLY with the producers' fold; then spin on the
//                   8 flags, acquire-fence, stage wv to LDS, dots + softmax.
// All 72 blocks are co-resident (2 blocks/CU by LDS, 256 CUs) -> no deadlock.
// Flags live in the poisoned workspace: each iteration's fill resets them,
// producers re-arm them -> no cross-iteration state.
// Per-block wv recompute (round 1) cost +6 us (64x cold-W); flag-sync keeps
// the single-W-read property while removing a launch + serialization.
// ---------------------------------------------------------------------------
__global__ __launch_bounds__(512) void gat_fused_kernel(
    const int* nn1, const int* nn2, const int* adj1, const int* adj2,
    const void* emb,
    const void* W1, const void* as1, const void* ad1, const void* b1,
    const void* W2, const void* as2, const void* ad2, const void* b2,
    const void* mlpw, const void* mlpb,
    float* wv, int f32arg, void* out)
{
    __shared__ float s_wv[24 * RS];            // 12.7 KB (producer: aliases s_av)
    __shared__ float s_rows[2 * MAXJ * RS];    // 42.2 KB (producer: aliases s_part)
    __shared__ int   s_nodes[2][Nn];           // 2 KB
    __shared__ int   s_srcj[2][MAXJ];
    __shared__ int   s_gid[2 * MAXJ];
    __shared__ int   s_cnt[2];
    __shared__ int   s_f32;
    __shared__ float s_ps[2 * MAXJ * Hh], s_pm[2 * MAXJ * Hh];
    __shared__ float s_pd[2 * Hh], s_hval[2 * Hh], s_bdot[2];
    __shared__ float s_red[2];

    const int tid = threadIdx.x;
    const int x = blockIdx.x;

    if (x < 8) {
        // ================= PRODUCER =================
        const int l = x >> 2, h = x & 3;
        float* s_av   = s_wv;     // 384 floats   [t][d]
        float* s_part = s_rows;   // 6144 floats  [dg][t][k]

        int f32 = f32arg;
        if (f32 < 0) {            // fallback dtype probe (host sizes implausible)
            if (tid < 64) {
                float v = bf2f(((const unsigned short*)W1)[tid]);
                unsigned long long m = __ballot(!(v > -64.f && v < 64.f));
                if (tid == 0) s_f32 = (m != 0ull) ? 1 : 0;
            }
            __syncthreads();
            f32 = s_f32;
        }

        // stage the 3 fold vectors for this (l,h)
        if (tid < 384) {
            int t = tid >> 7, d = tid & 127;
            const void* p; long off;
            if (t == 0)      { p = l ? as2 : as1; off = (long)h * Dd + d; }
            else if (t == 1) { p = l ? ad2 : ad1; off = (long)h * Dd + d; }
            else             { p = mlpw;          off = (long)l * Dd + d; }
            s_av[tid] = f32 ? ((const float*)p)[off]
                            : bf2f(((const unsigned short*)p)[off]);
        }
        __syncthreads();

        // coalesced fold: 512 threads = 32 col-groups x 16 d-groups of 8
        {
            const int kc = (tid & 31) * 4;
            const int dg = tid >> 5;          // 0..15
            const int d0 = dg * 8;
            float acc[3][4] = {};
            if (f32) {
                const float* Wf = (const float*)(l ? W2 : W1) + (long)h * Dd * Dd;
                #pragma unroll
                for (int dd = 0; dd < 8; ++dd) {
                    int d = d0 + dd;
                    float4 w = *(const float4*)(Wf + (long)d * Dd + kc);
                    #pragma unroll
                    for (int t = 0; t < 3; ++t) {
                        float a = s_av[t * Dd + d];
                        acc[t][0] += a * w.x; acc[t][1] += a * w.y;
                        acc[t][2] += a * w.z; acc[t][3] += a * w.w;
                    }
                }
            } else {
                const unsigned short* Wb =
                    (const unsigned short*)(l ? W2 : W1) + (long)h * Dd * Dd;
                #pragma unroll
                for (int dd = 0; dd < 8; ++dd) {
                    int d = d0 + dd;
                    ushort4 u = *(const ushort4*)(Wb + (long)d * Dd + kc);
                    float wx = bf2f(u.x), wy = bf2f(u.y);
                    float wz = bf2f(u.z), ww = bf2f(u.w);
                    #pragma unroll
                    for (int t = 0; t < 3; ++t) {
                        float a = s_av[t * Dd + d];
                        acc[t][0] += a * wx; acc[t][1] += a * wy;
                        acc[t][2] += a * wz; acc[t][3] += a * ww;
                    }
                }
            }
            const int dg2 = tid >> 5;
            #pragma unroll
            for (int t = 0; t < 3; ++t)
                *(float4*)&s_part[(dg2 * 3 + t) * Dd + kc] =
                    make_float4(acc[t][0], acc[t][1], acc[t][2], acc[t][3]);
        }
        __syncthreads();

        // combine 16 d-groups -> 3 wv rows of this (l,h)
        if (tid < 384) {
            int t = tid >> 7, k = tid & 127;
            float s = 0.f;
            #pragma unroll
            for (int g = 0; g < 16; ++g) s += s_part[(g * 3 + t) * Dd + k];
            wv[((l * 3 + t) * 4 + h) * Dd + k] = s;
        }

        // bdot (blocks h==0): dot(bias_l, mlp_half_l) (+ mlp_b for l==0)
        if (h == 0) {            // block-uniform branch: barrier inside is safe
            float p = 0.f;
            if (tid < 128) {
                const void* bias = l ? b2 : b1;
                float bv = f32 ? ((const float*)bias)[tid]
                               : bf2f(((const unsigned short*)bias)[tid]);
                p = bv * s_av[2 * Dd + tid];
            }
            #pragma unroll
            for (int off = 32; off > 0; off >>= 1) p += __shfl_down(p, off);
            if (tid == 0 || tid == 64) s_red[tid >> 6] = p;
            __syncthreads();
            if (tid == 0) {
                float a = s_red[0] + s_red[1];
                if (l == 0) a += f32 ? ((const float*)mlpb)[0]
                                     : bf2f(((const unsigned short*)mlpb)[0]);
                wv[3072 + l] = a;
            }
        }

        // release: drain all waves' stores, write back L2, then arm flag
        __threadfence();
        __syncthreads();
        if (tid == 0)
            atomicExch((unsigned*)wv + 3080 + x, MAGIC);
        return;
    }

    // ================= CONSUMER =================
    const int b = x - 8;

    // ---- pre-barrier phase: issue every independent load -----------------
    const int* adjp0 = adj1 + (long)b * 2 * Ee;
    const int* adjp1 = adj2 + (long)b * 2 * Ee;
    int4 d0 = ((const int4*)(adjp0 + Ee))[tid];   // dst halves (for ==0 test)
    int4 s0 = ((const int4*)adjp0)[tid];          // src halves (used on match)
    int4 d1 = ((const int4*)(adjp1 + Ee))[tid];
    int4 s1 = ((const int4*)adjp1)[tid];

    {   // node-id table: 512 threads == 2 layers x 256 nodes exactly
        int l = tid >> 8, n = tid & 255;
        s_nodes[l][n] = (l ? nn2 : nn1)[b * Nn + n];
    }
    if (tid < 2) s_cnt[tid] = 0;

    int f32 = f32arg;
    if (f32 < 0 && tid < 64) {    // fallback dtype probe
        float v = bf2f(((const unsigned short*)W1)[tid]);
        unsigned long long m = __ballot(!(v > -64.f && v < 64.f));
        if (tid == 0) s_f32 = (m != 0ull) ? 1 : 0;
    }
    __syncthreads();                                        // S1
    if (f32 < 0) f32 = s_f32;

    // ---- scan atomics (operands already in registers) --------------------
    {
        #define SCAN1(c, sv, l) \
            if ((c) == 0) { int p = atomicAdd(&s_cnt[l], 1); \
                            if (p < MAXJ - 1) s_srcj[l][p] = (sv); }
        SCAN1(d0.x, s0.x, 0) SCAN1(d0.y, s0.y, 0)
        SCAN1(d0.z, s0.z, 0) SCAN1(d0.w, s0.w, 0)
        SCAN1(d1.x, s1.x, 1) SCAN1(d1.y, s1.y, 1)
        SCAN1(d1.z, s1.z, 1) SCAN1(d1.w, s1.w, 1)
        #undef SCAN1
    }
    __syncthreads();                                        // S2

    // ---- counts + gid (self-loop fused in, row LAST within each layer) ---
    int c0 = s_cnt[0]; if (c0 > MAXJ - 1) c0 = MAXJ - 1; c0 += 1;
    int c1 = s_cnt[1]; if (c1 > MAXJ - 1) c1 = MAXJ - 1; c1 += 1;
    const int tot = c0 + c1;

    if (tid < 2 * MAXJ) {
        int l = tid >= MAXJ;
        int j = l ? tid - MAXJ : tid;
        int cl = l ? c1 : c0;
        int base = l ? c0 : 0;
        if (j < cl) {
            int src = (j == cl - 1) ? 0 : s_srcj[l][j];   // self-loop last
            s_gid[base + j] = s_nodes[l][src];
        }
    }
    __syncthreads();                                        // S3

    // ---- gather embedding rows (overlaps with producers' fold) -----------
    if (f32) {
        for (int idx = tid; idx < tot * 32; idx += 512) {
            int j = idx >> 5, k4 = (idx & 31) << 2;
            long gid = s_gid[j];
            float4 f = ((const float4*)emb)[gid * 32 + (k4 >> 2)];
            *(float4*)&s_rows[j * RS + k4] = f;
        }
    } else {
        for (int idx = tid; idx < tot * 16; idx += 512) {
            int j = idx >> 4, k8 = (idx & 15) << 3;
            long gid = s_gid[j];
            uint4 u = *(const uint4*)((const unsigned short*)emb + gid * Dd + k8);
            float4 f0 = make_float4(bf2f(u.x & 0xffff), bf2f(u.x >> 16),
                                    bf2f(u.y & 0xffff), bf2f(u.y >> 16));
            float4 f1 = make_float4(bf2f(u.z & 0xffff), bf2f(u.z >> 16),
                                    bf2f(u.w & 0xffff), bf2f(u.w >> 16));
            *(float4*)&s_rows[j * RS + k8] = f0;
            *(float4*)&s_rows[j * RS + k8 + 4] = f1;
        }
    }

    // ---- spin on producer flags, then acquire + stage wv -----------------
    if (tid < 8) {
        unsigned* fl = (unsigned*)wv + 3080 + tid;
        while (atomicAdd(fl, 0u) != MAGIC) __builtin_amdgcn_s_sleep(2);
    }
    __syncthreads();                                        // S4
    __threadfence();   // acquire: invalidate stale cached wv lines

    for (int i = tid; i < 768; i += 512) {
        float4 f = ((const float4*)wv)[i];
        int el = i * 4, row = el >> 7, k = el & 127;
        *(float4*)&s_wv[row * RS + k] = f;
    }
    if (tid < 2) s_bdot[tid] = wv[3072 + tid];
    __syncthreads();                                        // S5

    // ---- dots: per row j: (asrc, pm) per head; + per (l,h): adst(center) --
    const int ntask = tot * 8 + 8;
    for (int task = tid; task < ntask; task += 512) {
        int j, h, t, l;
        if (task < tot * 8) {
            j = task >> 3; h = (task >> 1) & 3; t = (task & 1) ? 2 : 0;
            l = (j < c0) ? 0 : 1;
        } else {
            int z = task - tot * 8;       // 0..7
            l = z >> 2; h = z & 3; t = 1;
            j = l ? (tot - 1) : (c0 - 1);   // self-loop row = center node
        }
        const float4* r4 = (const float4*)(s_rows + j * RS);
        const float4* w4 = (const float4*)(s_wv + ((l * 3 + t) * Hh + h) * RS);
        float acc = 0.f;
        #pragma unroll 8
        for (int k = 0; k < 32; ++k) {
            float4 a = r4[k], w = w4[k];
            acc += a.x * w.x + a.y * w.y + a.z * w.z + a.w * w.w;
        }
        if (task < tot * 8) {
            if (task & 1) s_pm[j * Hh + h] = acc;
            else          s_ps[j * Hh + h] = acc;
        } else {
            s_pd[(l << 2) | h] = acc;
        }
    }
    __syncthreads();                                        // S6

    // ---- wave-parallel softmax: wave w=(l,h), lanes parallel over j ------
    {
        const int w = tid >> 6, lane = tid & 63;
        const int l = w >> 2, h = w & 3;
        const int j0 = l ? c0 : 0;
        const int cntl = (l ? tot : c0) - j0;     // <= MAXJ <= 64 lanes
        const float pd = s_pd[w];
        const bool valid = lane < cntl;
        const int j = j0 + (valid ? lane : 0);
        float e = valid ? (s_ps[j * Hh + h] + pd) : -1e30f;
        e = (e >= 0.f) ? e : 0.2f * e;            // leaky relu, slope 0.2
        float m = e;
        #pragma unroll
        for (int off = 32; off > 0; off >>= 1)
            m = fmaxf(m, __shfl_xor(m, off));
        float ex = valid ? expf(e - m) : 0.f;
        float pm = valid ? s_pm[j * Hh + h] : 0.f;
        float den = ex, num = ex * pm;
        #pragma unroll
        for (int off = 32; off > 0; off >>= 1) {
            den += __shfl_xor(den, off);
            num += __shfl_xor(num, off);
        }
        if (lane == 0) s_hval[w] = num / den;
    }
    __syncthreads();                                        // S7

    if (tid == 0) {
        float r = 0.25f * (s_hval[0] + s_hval[1] + s_hval[2] + s_hval[3]) + s_bdot[0]
                + 0.25f * (s_hval[4] + s_hval[5] + s_hval[6] + s_hval[7]) + s_bdot[1];
        if (f32) ((float*)out)[b] = r;
        else     ((__hip_bfloat16*)out)[b] = __float2bfloat16(r);
    }
}

extern "C" void kernel_launch(void* const* d_in, const int* in_sizes, int n_in,
                              void* d_out, int out_size, void* d_ws, size_t ws_size,
                              hipStream_t stream) {
    float* wv = (float*)d_ws;   // floats 0..3073 = wv+bdot; words 3080..3087 = flags

    // dtype from host-side byte sizes (W1 = 512x128 elems); -1 -> device probe
    int sz5 = (in_sizes && n_in > 5) ? in_sizes[5] : 0;
    int f32arg = (sz5 == 512 * 128 * 4) ? 1 : ((sz5 == 512 * 128 * 2) ? 0 : -1);

    gat_fused_kernel<<<8 + Bg, 512, 0, stream>>>(
        (const int*)d_in[0],  /* nn1 */
        (const int*)d_in[1],  /* nn2 */
        (const int*)d_in[2],  /* adj1 */
        (const int*)d_in[3],  /* adj2 */
        d_in[4],  /* emb */
        d_in[5],  /* W1  */ d_in[6],  /* as1 */ d_in[7],  /* ad1 */
        d_in[8],  /* b1  */
        d_in[9],  /* W2  */ d_in[10], /* as2 */ d_in[11], /* ad2 */
        d_in[12], /* b2  */
        d_in[13], /* mlpw */ d_in[14], /* mlpb */
        wv, f32arg, d_out);
}

// Round 4
// 106.181 us; speedup vs baseline: 1.0501x; 1.0501x over previous
//
#include <hip/hip_runtime.h>
#include <hip/hip_bf16.h>

// Problem constants (from reference)
#define Bg 64       // graphs
#define Nn 256      // nodes per subgraph
#define Ee 2048     // edges per subgraph
#define Dd 128      // hidden dim
#define Hh 4        // heads
#define MAXJ 40     // cap on in-edges of node 0 (+self) per layer; Binom(2048,1/256): P(>38)~1e-17
#define RS 132      // LDS row stride (128 + 4 pad)

__device__ __forceinline__ float bf2f(unsigned short u) {
    return __uint_as_float(((unsigned)u) << 16);
}

// ---------------------------------------------------------------------------
// ONE kernel, 64 blocks x 512 threads, NO workspace, NO cross-block sync.
// Each block recomputes the 24-row folded-weight table wv in-LDS — but cheap:
//  - Wave w=(l,h) folds {att_src, att_dst, mlp half} through W_l[h] with 16B
//    per-lane loads (f32: 64x float4; bf16: 32x uint4), all independent ->
//    ~1 memory round trip. All 64 blocks read the SAME W lines -> one HBM
//    fetch + L3 broadcast (r1's mistake: 4B/lane loads + 384 scalar LDS reads
//    per lane = ~3 us/block; r3's mistake: RMW-spin convoy on one line).
//  - d-partials reduced via __shfl_xor butterfly (no LDS round trip).
//  - T14 async-split gather: per-thread emb loads issued into REGISTERS before
//    the fold, converted/stored to LDS after -> gather HBM latency hides under
//    the fold's FMA stream.
// 64 blocks <= 256 CUs: every block gets its own CU; co-residency trivial.
// ---------------------------------------------------------------------------
__global__ __launch_bounds__(512) void gat_fused_kernel(
    const int* nn1, const int* nn2, const int* adj1, const int* adj2,
    const void* emb,
    const void* W1, const void* as1, const void* ad1, const void* b1,
    const void* W2, const void* as2, const void* ad2, const void* b2,
    const void* mlpw, const void* mlpb, int f32arg, void* out)
{
    __shared__ float s_wv[24 * RS];            // 12.7 KB folded rows (computed in-block)
    __shared__ float s_rows[2 * MAXJ * RS];    // 42.2 KB gathered emb rows
    __shared__ float s_att[2304];              // 9.2 KB  [(l*2+t)*4+h][128] + mlp at 2048+l*128
    __shared__ int   s_nodes[2][Nn];           // 2 KB
    __shared__ int   s_srcj[2][MAXJ];
    __shared__ int   s_gid[2 * MAXJ];
    __shared__ int   s_cnt[2];
    __shared__ int   s_f32;
    __shared__ float s_ps[2 * MAXJ * Hh], s_pm[2 * MAXJ * Hh];
    __shared__ float s_pd[8], s_hval[8];
    __shared__ float s_red[4];

    const int tid = threadIdx.x;
    const int b = blockIdx.x;

    // ---- pre-barrier phase: issue every independent load -----------------
    const int* adjp0 = adj1 + (long)b * 2 * Ee;
    const int* adjp1 = adj2 + (long)b * 2 * Ee;
    int4 d0 = ((const int4*)(adjp0 + Ee))[tid];   // dst halves (for ==0 test)
    int4 s0 = ((const int4*)adjp0)[tid];          // src halves (used on match)
    int4 d1 = ((const int4*)(adjp1 + Ee))[tid];
    int4 s1 = ((const int4*)adjp1)[tid];

    {   // node-id table: 512 threads == 2 layers x 256 nodes exactly
        int l = tid >> 8, n = tid & 255;
        s_nodes[l][n] = (l ? nn2 : nn1)[b * Nn + n];
    }
    if (tid < 2) s_cnt[tid] = 0;

    int f32 = f32arg;
    if (f32 < 0) {   // fallback dtype probe (host byte-sizes implausible)
        if (tid < 64) {
            float v = bf2f(((const unsigned short*)W1)[tid]);
            unsigned long long m = __ballot(!(v > -64.f && v < 64.f));
            if (tid == 0) s_f32 = (m != 0ull) ? 1 : 0;
        }
        __syncthreads();
        f32 = s_f32;
    }

    // stage att vectors (as/ad x 2 layers x 4 heads) + mlp halves as f32
    if (f32) {
        for (int i = tid; i < 576; i += 512) {
            int e = i * 4;
            const float* p; int dst;
            if (e < 2048) {
                int l = e >> 10, t = (e >> 9) & 1, h = (e >> 7) & 3, d = e & 127;
                p = (const float*)(l ? (t ? ad2 : as2) : (t ? ad1 : as1)) + h * Dd + d;
                dst = ((l * 2 + t) * 4 + h) * Dd + d;
            } else {
                p = (const float*)mlpw + (e - 2048);
                dst = e;
            }
            *(float4*)&s_att[dst] = *(const float4*)p;
        }
    } else {
        if (tid < 288) {
            int e = tid * 8;
            const unsigned short* p; int dst;
            if (e < 2048) {
                int l = e >> 10, t = (e >> 9) & 1, h = (e >> 7) & 3, d = e & 127;
                p = (const unsigned short*)(l ? (t ? ad2 : as2) : (t ? ad1 : as1)) + h * Dd + d;
                dst = ((l * 2 + t) * 4 + h) * Dd + d;
            } else {
                p = (const unsigned short*)mlpw + (e - 2048);
                dst = e;
            }
            uint4 u = *(const uint4*)p;
            *(float4*)&s_att[dst] = make_float4(bf2f(u.x & 0xffff), bf2f(u.x >> 16),
                                                bf2f(u.y & 0xffff), bf2f(u.y >> 16));
            *(float4*)&s_att[dst + 4] = make_float4(bf2f(u.z & 0xffff), bf2f(u.z >> 16),
                                                    bf2f(u.w & 0xffff), bf2f(u.w >> 16));
        }
    }

    // bias + mlpb preloads (registers; consumed by bdot reduce post-S3)
    float bv = 0.f;
    if (tid < 256) {
        int l = tid >> 7, d = tid & 127;
        const void* bp = l ? b2 : b1;
        bv = f32 ? ((const float*)bp)[d] : bf2f(((const unsigned short*)bp)[d]);
    }
    float mb = 0.f;
    if (tid == 0)
        mb = f32 ? ((const float*)mlpb)[0] : bf2f(((const unsigned short*)mlpb)[0]);

    __syncthreads();                                        // S1

    // ---- scan atomics (operands already in registers) --------------------
    {
        #define SCAN1(c, sv, l) \
            if ((c) == 0) { int p = atomicAdd(&s_cnt[l], 1); \
                            if (p < MAXJ - 1) s_srcj[l][p] = (sv); }
        SCAN1(d0.x, s0.x, 0) SCAN1(d0.y, s0.y, 0)
        SCAN1(d0.z, s0.z, 0) SCAN1(d0.w, s0.w, 0)
        SCAN1(d1.x, s1.x, 1) SCAN1(d1.y, s1.y, 1)
        SCAN1(d1.z, s1.z, 1) SCAN1(d1.w, s1.w, 1)
        #undef SCAN1
    }
    __syncthreads();                                        // S2

    // ---- counts + gid (self-loop fused in, row LAST within each layer) ---
    int c0 = s_cnt[0]; if (c0 > MAXJ - 1) c0 = MAXJ - 1; c0 += 1;
    int c1 = s_cnt[1]; if (c1 > MAXJ - 1) c1 = MAXJ - 1; c1 += 1;
    const int tot = c0 + c1;

    if (tid < 2 * MAXJ) {
        int l = tid >= MAXJ;
        int j = l ? tid - MAXJ : tid;
        int cl = l ? c1 : c0;
        int base = l ? c0 : 0;
        if (j < cl) {
            int src = (j == cl - 1) ? 0 : s_srcj[l][j];   // self-loop last
            s_gid[base + j] = s_nodes[l][src];
        }
    }
    __syncthreads();                                        // S3

    // ---- (a) gather loads into REGISTERS (T14 issue-early) ---------------
    const int na = f32 ? tot * 32 : tot * 16;
    float4 ga, gb; uint4 ua;
    bool va = false, vb = false;
    if (f32) {
        if (tid < na) {
            int j = tid >> 5, k4 = (tid & 31) << 2;
            ga = ((const float4*)emb)[(long)s_gid[j] * 32 + (k4 >> 2)];
            va = true;
        }
        int t2 = tid + 512;
        if (t2 < na) {
            int j = t2 >> 5, k4 = (t2 & 31) << 2;
            gb = ((const float4*)emb)[(long)s_gid[j] * 32 + (k4 >> 2)];
            vb = true;
        }
    } else {
        if (tid < na) {
            int j = tid >> 4, k8 = (tid & 15) << 3;
            ua = *(const uint4*)((const unsigned short*)emb + (long)s_gid[j] * Dd + k8);
            va = true;
        }
    }

    // ---- (b) wv fold (overlaps gather latency): wave w = (l,h) -----------
    {
        const int w = tid >> 6, lane = tid & 63;
        const int l = w >> 2, h = w & 3;
        const float* a0 = s_att + ((l * 2 + 0) * 4 + h) * Dd;   // att_src
        const float* a1 = s_att + ((l * 2 + 1) * 4 + h) * Dd;   // att_dst
        const float* a2 = s_att + 2048 + l * Dd;                // mlp half
        if (f32) {
            const int k0 = (lane & 31) * 4;                     // 32 col-groups x 4
            const int d0f = (lane >> 5) * 64;                   // 2 d-groups x 64
            const float* Wf = (const float*)(l ? W2 : W1) + h * Dd * Dd;
            float acc[3][4] = {};
            #pragma unroll 8
            for (int i = 0; i < 64; ++i) {
                int d = d0f + i;
                float4 wr = *(const float4*)(Wf + d * Dd + k0);
                float x0 = a0[d], x1 = a1[d], x2 = a2[d];
                acc[0][0] += x0 * wr.x; acc[0][1] += x0 * wr.y;
                acc[0][2] += x0 * wr.z; acc[0][3] += x0 * wr.w;
                acc[1][0] += x1 * wr.x; acc[1][1] += x1 * wr.y;
                acc[1][2] += x1 * wr.z; acc[1][3] += x1 * wr.w;
                acc[2][0] += x2 * wr.x; acc[2][1] += x2 * wr.y;
                acc[2][2] += x2 * wr.z; acc[2][3] += x2 * wr.w;
            }
            #pragma unroll
            for (int t = 0; t < 3; ++t)
                #pragma unroll
                for (int c = 0; c < 4; ++c)
                    acc[t][c] += __shfl_xor(acc[t][c], 32);
            if (lane < 32) {
                #pragma unroll
                for (int t = 0; t < 3; ++t)
                    *(float4*)&s_wv[((l * 3 + t) * 4 + h) * RS + k0] =
                        make_float4(acc[t][0], acc[t][1], acc[t][2], acc[t][3]);
            }
        } else {
            const int k0 = (lane & 15) * 8;                     // 16 col-groups x 8
            const int d0b = (lane >> 4) * 32;                   // 4 d-groups x 32
            const unsigned short* Wb =
                (const unsigned short*)(l ? W2 : W1) + h * Dd * Dd;
            float acc[3][8] = {};
            #pragma unroll 4
            for (int i = 0; i < 32; ++i) {
                int d = d0b + i;
                uint4 u = *(const uint4*)(Wb + d * Dd + k0);
                float wc[8] = { bf2f(u.x & 0xffff), bf2f(u.x >> 16),
                                bf2f(u.y & 0xffff), bf2f(u.y >> 16),
                                bf2f(u.z & 0xffff), bf2f(u.z >> 16),
                                bf2f(u.w & 0xffff), bf2f(u.w >> 16) };
                float x0 = a0[d], x1 = a1[d], x2 = a2[d];
                #pragma unroll
                for (int c = 0; c < 8; ++c) {
                    acc[0][c] += x0 * wc[c];
                    acc[1][c] += x1 * wc[c];
                    acc[2][c] += x2 * wc[c];
                }
            }
            #pragma unroll
            for (int t = 0; t < 3; ++t)
                #pragma unroll
                for (int c = 0; c < 8; ++c) {
                    acc[t][c] += __shfl_xor(acc[t][c], 16);
                    acc[t][c] += __shfl_xor(acc[t][c], 32);
                }
            if (lane < 16) {
                #pragma unroll
                for (int t = 0; t < 3; ++t) {
                    *(float4*)&s_wv[((l * 3 + t) * 4 + h) * RS + k0] =
                        make_float4(acc[t][0], acc[t][1], acc[t][2], acc[t][3]);
                    *(float4*)&s_wv[((l * 3 + t) * 4 + h) * RS + k0 + 4] =
                        make_float4(acc[t][4], acc[t][5], acc[t][6], acc[t][7]);
                }
            }
        }
    }

    // ---- (c) bdot partials: dot(bias_l, mlp_l) via shfl ------------------
    {
        float p = (tid < 256) ? bv * s_att[2048 + ((tid >> 7) * Dd) + (tid & 127)] : 0.f;
        #pragma unroll
        for (int off = 32; off > 0; off >>= 1) p += __shfl_down(p, off);
        if (tid < 256 && (tid & 63) == 0) s_red[tid >> 6] = p;
    }

    // ---- (d) gather stores (loads have been in flight through the fold) --
    if (f32) {
        if (va) {
            int j = tid >> 5, k4 = (tid & 31) << 2;
            *(float4*)&s_rows[j * RS + k4] = ga;
        }
        if (vb) {
            int t2 = tid + 512, j = t2 >> 5, k4 = (t2 & 31) << 2;
            *(float4*)&s_rows[j * RS + k4] = gb;
        }
        for (int idx = tid + 1024; idx < na; idx += 512) {   // tot>32: ~never
            int j = idx >> 5, k4 = (idx & 31) << 2;
            *(float4*)&s_rows[j * RS + k4] =
                ((const float4*)emb)[(long)s_gid[j] * 32 + (k4 >> 2)];
        }
    } else {
        if (va) {
            int j = tid >> 4, k8 = (tid & 15) << 3;
            *(float4*)&s_rows[j * RS + k8] =
                make_float4(bf2f(ua.x & 0xffff), bf2f(ua.x >> 16),
                            bf2f(ua.y & 0xffff), bf2f(ua.y >> 16));
            *(float4*)&s_rows[j * RS + k8 + 4] =
                make_float4(bf2f(ua.z & 0xffff), bf2f(ua.z >> 16),
                            bf2f(ua.w & 0xffff), bf2f(ua.w >> 16));
        }
        for (int idx = tid + 512; idx < na; idx += 512) {    // tot>32: ~never
            int j = idx >> 4, k8 = (idx & 15) << 3;
            uint4 u = *(const uint4*)((const unsigned short*)emb + (long)s_gid[j] * Dd + k8);
            *(float4*)&s_rows[j * RS + k8] =
                make_float4(bf2f(u.x & 0xffff), bf2f(u.x >> 16),
                            bf2f(u.y & 0xffff), bf2f(u.y >> 16));
            *(float4*)&s_rows[j * RS + k8 + 4] =
                make_float4(bf2f(u.z & 0xffff), bf2f(u.z >> 16),
                            bf2f(u.w & 0xffff), bf2f(u.w >> 16));
        }
    }
    __syncthreads();                                        // S4

    // ---- dots: per row j: (asrc, pm) per head; + per (l,h): adst(center) --
    const int ntask = tot * 8 + 8;
    for (int task = tid; task < ntask; task += 512) {
        int j, h, t, l;
        if (task < tot * 8) {
            j = task >> 3; h = (task >> 1) & 3; t = (task & 1) ? 2 : 0;
            l = (j < c0) ? 0 : 1;
        } else {
            int z = task - tot * 8;       // 0..7
            l = z >> 2; h = z & 3; t = 1;
            j = l ? (tot - 1) : (c0 - 1);   // self-loop row = center node
        }
        const float4* r4 = (const float4*)(s_rows + j * RS);
        const float4* w4 = (const float4*)(s_wv + ((l * 3 + t) * Hh + h) * RS);
        float acc = 0.f;
        #pragma unroll 8
        for (int k = 0; k < 32; ++k) {
            float4 a = r4[k], w = w4[k];
            acc += a.x * w.x + a.y * w.y + a.z * w.z + a.w * w.w;
        }
        if (task < tot * 8) {
            if (task & 1) s_pm[j * Hh + h] = acc;
            else          s_ps[j * Hh + h] = acc;
        } else {
            s_pd[(l << 2) | h] = acc;
        }
    }
    __syncthreads();                                        // S5

    // ---- wave-parallel softmax: wave w=(l,h), lanes parallel over j ------
    {
        const int w = tid >> 6, lane = tid & 63;
        const int l = w >> 2, h = w & 3;
        const int j0 = l ? c0 : 0;
        const int cntl = (l ? tot : c0) - j0;     // <= MAXJ <= 64 lanes
        const float pd = s_pd[w];
        const bool valid = lane < cntl;
        const int j = j0 + (valid ? lane : 0);
        float e = valid ? (s_ps[j * Hh + h] + pd) : -1e30f;
        e = (e >= 0.f) ? e : 0.2f * e;            // leaky relu, slope 0.2
        float m = e;
        #pragma unroll
        for (int off = 32; off > 0; off >>= 1)
            m = fmaxf(m, __shfl_xor(m, off));
        float ex = valid ? expf(e - m) : 0.f;
        float pm = valid ? s_pm[j * Hh + h] : 0.f;
        float den = ex, num = ex * pm;
        #pragma unroll
        for (int off = 32; off > 0; off >>= 1) {
            den += __shfl_xor(den, off);
            num += __shfl_xor(num, off);
        }
        if (lane == 0) s_hval[w] = num / den;
    }
    __syncthreads();                                        // S6

    if (tid == 0) {
        float bd0 = s_red[0] + s_red[1] + mb;
        float bd1 = s_red[2] + s_red[3];
        float r = 0.25f * (s_hval[0] + s_hval[1] + s_hval[2] + s_hval[3]) + bd0
                + 0.25f * (s_hval[4] + s_hval[5] + s_hval[6] + s_hval[7]) + bd1;
        if (f32) ((float*)out)[b] = r;
        else     ((__hip_bfloat16*)out)[b] = __float2bfloat16(r);
    }
}

extern "C" void kernel_launch(void* const* d_in, const int* in_sizes, int n_in,
                              void* d_out, int out_size, void* d_ws, size_t ws_size,
                              hipStream_t stream) {
    // dtype from host-side byte sizes (W1 = 512x128 elems); -1 -> device probe
    int sz5 = (in_sizes && n_in > 5) ? in_sizes[5] : 0;
    int f32arg = (sz5 == 512 * 128 * 4) ? 1 : ((sz5 == 512 * 128 * 2) ? 0 : -1);

    gat_fused_kernel<<<Bg, 512, 0, stream>>>(
        (const int*)d_in[0],  /* nn1 */
        (const int*)d_in[1],  /* nn2 */
        (const int*)d_in[2],  /* adj1 */
        (const int*)d_in[3],  /* adj2 */
        d_in[4],  /* emb */
        d_in[5],  /* W1  */ d_in[6],  /* as1 */ d_in[7],  /* ad1 */
        d_in[8],  /* b1  */
        d_in[9],  /* W2  */ d_in[10], /* as2 */ d_in[11], /* ad2 */
        d_in[12], /* b2  */
        d_in[13], /* mlpw */ d_in[14], /* mlpb */
        f32arg, d_out);
}

// Round 5
// 103.401 us; speedup vs baseline: 1.0784x; 1.0269x over previous
//
#include <hip/hip_runtime.h>
#include <hip/hip_bf16.h>

// Problem constants (from reference)
#define Bg 64       // graphs
#define Nn 256      // nodes per subgraph
#define Ee 2048     // edges per subgraph
#define Dd 128      // hidden dim
#define Hh 4        // heads
#define MAXJ 40     // cap on in-edges of node 0 (+self) per layer; Binom(2048,1/256): P(>38)~1e-17
#define RS 132      // LDS row stride (128 + 4 pad)

__device__ __forceinline__ float bf2f(unsigned short u) {
    return __uint_as_float(((unsigned)u) << 16);
}

// ---------------------------------------------------------------------------
// Two-kernel structure: measured best (104.3 us r2 vs fused 106.2/110.5/111.5).
// Three fusion strategies all regressed:
//  - per-block wv recompute, naive (r1): +6 us — 64x cold-W + scalar LDS fold
//  - producer/consumer flag sync (r3):  +7 us — device-RMW spin convoy
//  - per-block recompute, 16B-lane fold + T14 overlap (r4): +2 us — per-block
//    cold W/L3 read + extra phases on all 64 blocks > one saved launch.
// Kernel 1 reads W once chip-wide (8 blocks); kernel 2 reads only the 12 KB
// folded table. Remaining time = 2 x 43.5 us harness poison fills (HBM
// roofline) + ~17 us kernels/launch overhead.
// ---------------------------------------------------------------------------

// Kernel 1: wv fold + bdot, fully COALESCED W reads.
// Grid: 8 blocks = (l = x>>2, h = x&3), 256 threads.
//   wv[((l*3+t)*4+h)*128 + k] = sum_d av_t[d] * W_l[h*128+d, k]
//     t: 0=att_src, 1=att_dst, 2=mlp half.  wv[3072+l] = bdot_l.
__global__ __launch_bounds__(256) void precompute_kernel(
    const void* W1, const void* as1, const void* ad1, const void* b1,
    const void* W2, const void* as2, const void* ad2, const void* b2,
    const void* mlpw, const void* mlpb, float* wv)
{
    __shared__ float s_av[3 * Dd];         // [t][d]
    __shared__ float s_part[8 * 3 * Dd];   // [dg][t][k]  12 KB
    __shared__ float s_red[2];
    __shared__ int   s_f32;

    const int tid = threadIdx.x;
    const int x = blockIdx.x;
    const int l = x >> 2, h = x & 3;

    // dtype probe (W1 is read by this kernel anyway; zero marginal cost)
    if (tid < 64) {
        float v = bf2f(((const unsigned short*)W1)[tid]);
        bool bad = !(v > -64.f && v < 64.f);
        unsigned long long m = __ballot(bad);
        if (tid == 0) s_f32 = (m != 0ull) ? 1 : 0;
    }
    __syncthreads();
    const int f32 = s_f32;

    // stage the 3 attention vectors for this (l,h)
    for (int i = tid; i < 3 * Dd; i += 256) {
        int t = i >> 7, d = i & 127;
        const void* p; long off;
        if (t == 0)      { p = l ? as2 : as1; off = (long)h * Dd + d; }
        else if (t == 1) { p = l ? ad2 : ad1; off = (long)h * Dd + d; }
        else             { p = mlpw;          off = (long)l * Dd + d; }
        s_av[i] = f32 ? ((const float*)p)[off]
                      : bf2f(((const unsigned short*)p)[off]);
    }
    __syncthreads();

    // coalesced fold
    {
        const int kc = (tid & 31) * 4;
        const int d0 = (tid >> 5) * 16;
        float acc[3][4] = {};
        if (f32) {
            const float* Wf = (const float*)(l ? W2 : W1) + (long)h * Dd * Dd;
            #pragma unroll
            for (int dd = 0; dd < 16; ++dd) {
                int d = d0 + dd;
                float4 w = *(const float4*)(Wf + (long)d * Dd + kc);
                #pragma unroll
                for (int t = 0; t < 3; ++t) {
                    float a = s_av[t * Dd + d];
                    acc[t][0] += a * w.x; acc[t][1] += a * w.y;
                    acc[t][2] += a * w.z; acc[t][3] += a * w.w;
                }
            }
        } else {
            const unsigned short* Wb =
                (const unsigned short*)(l ? W2 : W1) + (long)h * Dd * Dd;
            #pragma unroll
            for (int dd = 0; dd < 16; ++dd) {
                int d = d0 + dd;
                ushort4 u = *(const ushort4*)(Wb + (long)d * Dd + kc);
                float wx = bf2f(u.x), wy = bf2f(u.y);
                float wz = bf2f(u.z), ww = bf2f(u.w);
                #pragma unroll
                for (int t = 0; t < 3; ++t) {
                    float a = s_av[t * Dd + d];
                    acc[t][0] += a * wx; acc[t][1] += a * wy;
                    acc[t][2] += a * wz; acc[t][3] += a * ww;
                }
            }
        }
        const int dg = tid >> 5;
        #pragma unroll
        for (int t = 0; t < 3; ++t)
            *(float4*)&s_part[(dg * 3 + t) * Dd + kc] =
                make_float4(acc[t][0], acc[t][1], acc[t][2], acc[t][3]);
    }
    __syncthreads();

    // combine 8 d-groups -> 3 wv rows of this (l,h)
    for (int i = tid; i < 3 * Dd; i += 256) {
        int t = i >> 7, k = i & 127;
        float s = 0.f;
        #pragma unroll
        for (int g = 0; g < 8; ++g) s += s_part[(g * 3 + t) * Dd + k];
        wv[((l * 3 + t) * 4 + h) * Dd + k] = s;
    }

    // bdot (blocks h==0): dot(bias_l, mlp_half_l) (+ mlp_b for l==0)
    if (h == 0) {
        float p = 0.f;
        if (tid < 128) {
            const void* bias = l ? b2 : b1;
            float bv = f32 ? ((const float*)bias)[tid]
                           : bf2f(((const unsigned short*)bias)[tid]);
            p = bv * s_av[2 * Dd + tid];
        }
        #pragma unroll
        for (int off = 32; off > 0; off >>= 1) p += __shfl_down(p, off);
        if (tid == 0 || tid == 64) s_red[tid >> 6] = p;
        __syncthreads();
        if (tid == 0) {
            float a = s_red[0] + s_red[1];
            if (l == 0) a += f32 ? ((const float*)mlpb)[0]
                                 : bf2f(((const unsigned short*)mlpb)[0]);
            wv[3072 + l] = a;
        }
    }
}

// ---------------------------------------------------------------------------
// Kernel 2: one block per graph, both layers, 512 threads (8 waves).
//  - ALL independent HBM loads (adj dst AND src int4s, node table) issued
//    before the first barrier; dtype comes from the HOST (no cold W1 probe).
//  - Self-loop append fused into the gid phase.
//  - Dots are HALF-SPLIT: each 128-FMA dot = two 64-FMA tasks (partials
//    summed at softmax read) -> 2x task parallelism, half the dep chain.
//  - Softmax is wave-parallel: wave w=(l,h), lanes over in-edges, __shfl_xor.
// ---------------------------------------------------------------------------
__global__ __launch_bounds__(512) void gat_main_kernel(
    const int* nn1, const int* nn2, const int* adj1, const int* adj2,
    const void* emb, const void* W1, const float* wv, int f32arg, void* out)
{
    __shared__ float s_wv[24 * RS];            // 12.7 KB
    __shared__ float s_rows[2 * MAXJ * RS];    // 42.2 KB
    __shared__ int   s_nodes[2][Nn];           // 2 KB
    __shared__ int   s_srcj[2][MAXJ];
    __shared__ int   s_gid[2 * MAXJ];
    __shared__ int   s_cnt[2];
    __shared__ int   s_f32;
    __shared__ float s_ps[2 * MAXJ * Hh * 2], s_pm[2 * MAXJ * Hh * 2];
    __shared__ float s_pd[2 * Hh * 2], s_hval[2 * Hh], s_bdot[2];

    const int tid = threadIdx.x;
    const int b = blockIdx.x;

    // ---- pre-barrier phase: issue every independent load -----------------
    const int* adjp0 = adj1 + (long)b * 2 * Ee;
    const int* adjp1 = adj2 + (long)b * 2 * Ee;
    int4 d0 = ((const int4*)(adjp0 + Ee))[tid];   // dst halves (for ==0 test)
    int4 s0 = ((const int4*)adjp0)[tid];          // src halves (used on match)
    int4 d1 = ((const int4*)(adjp1 + Ee))[tid];
    int4 s1 = ((const int4*)adjp1)[tid];

    {   // node-id table: 512 threads == 2 layers x 256 nodes exactly
        int l = tid >> 8, n = tid & 255;
        s_nodes[l][n] = (l ? nn2 : nn1)[b * Nn + n];
    }
    if (tid < 2) s_cnt[tid] = 0;

    int f32 = f32arg;
    if (f32 < 0 && tid < 64) {    // fallback dtype probe (host sizes odd)
        float v = bf2f(((const unsigned short*)W1)[tid]);
        unsigned long long m = __ballot(!(v > -64.f && v < 64.f));
        if (tid == 0) s_f32 = (m != 0ull) ? 1 : 0;
    }
    __syncthreads();                                        // S1
    if (f32 < 0) f32 = s_f32;

    // ---- scan atomics (operands already in registers) --------------------
    {
        #define SCAN1(c, sv, l) \
            if ((c) == 0) { int p = atomicAdd(&s_cnt[l], 1); \
                            if (p < MAXJ - 1) s_srcj[l][p] = (sv); }
        SCAN1(d0.x, s0.x, 0) SCAN1(d0.y, s0.y, 0)
        SCAN1(d0.z, s0.z, 0) SCAN1(d0.w, s0.w, 0)
        SCAN1(d1.x, s1.x, 1) SCAN1(d1.y, s1.y, 1)
        SCAN1(d1.z, s1.z, 1) SCAN1(d1.w, s1.w, 1)
        #undef SCAN1
    }

    // wv stage (768 float4 / 512 threads = 2 iters) + bdot
    for (int i = tid; i < 768; i += 512) {
        float4 f = ((const float4*)wv)[i];
        int el = i * 4, row = el >> 7, k = el & 127;
        *(float4*)&s_wv[row * RS + k] = f;
    }
    if (tid < 2) s_bdot[tid] = wv[3072 + tid];
    __syncthreads();                                        // S2

    // ---- counts + gid (self-loop fused in, row LAST within each layer) ---
    int c0 = s_cnt[0]; if (c0 > MAXJ - 1) c0 = MAXJ - 1; c0 += 1;
    int c1 = s_cnt[1]; if (c1 > MAXJ - 1) c1 = MAXJ - 1; c1 += 1;
    const int tot = c0 + c1;

    if (tid < 2 * MAXJ) {
        int l = tid >= MAXJ;
        int j = l ? tid - MAXJ : tid;
        int cl = l ? c1 : c0;
        int base = l ? c0 : 0;
        if (j < cl) {
            int src = (j == cl - 1) ? 0 : s_srcj[l][j];   // self-loop last
            s_gid[base + j] = s_nodes[l][src];
        }
    }
    __syncthreads();                                        // S3

    // ---- gather embedding rows ------------------------------------------
    if (f32) {
        for (int idx = tid; idx < tot * 32; idx += 512) {
            int j = idx >> 5, k4 = (idx & 31) << 2;
            long gid = s_gid[j];
            float4 f = ((const float4*)emb)[gid * 32 + (k4 >> 2)];
            *(float4*)&s_rows[j * RS + k4] = f;
        }
    } else {
        for (int idx = tid; idx < tot * 16; idx += 512) {
            int j = idx >> 4, k8 = (idx & 15) << 3;
            long gid = s_gid[j];
            uint4 u = *(const uint4*)((const unsigned short*)emb + gid * Dd + k8);
            float4 f0 = make_float4(bf2f(u.x & 0xffff), bf2f(u.x >> 16),
                                    bf2f(u.y & 0xffff), bf2f(u.y >> 16));
            float4 f1 = make_float4(bf2f(u.z & 0xffff), bf2f(u.z >> 16),
                                    bf2f(u.w & 0xffff), bf2f(u.w >> 16));
            *(float4*)&s_rows[j * RS + k8] = f0;
            *(float4*)&s_rows[j * RS + k8 + 4] = f1;
        }
    }
    __syncthreads();                                        // S4

    // ---- dots (half-split): task = (old_task, kk half) -------------------
    // old_task < tot*8: row j, head h, t in {asrc, pm}; else adst(center).
    const int ntask = (tot * 8 + 8) * 2;
    for (int task = tid; task < ntask; task += 512) {
        const int kk = task & 1;          // which 64-element half of the dot
        const int t0 = task >> 1;
        int j, h, t, l;
        if (t0 < tot * 8) {
            j = t0 >> 3; h = (t0 >> 1) & 3; t = (t0 & 1) ? 2 : 0;
            l = (j < c0) ? 0 : 1;
        } else {
            int z = t0 - tot * 8;         // 0..7
            l = z >> 2; h = z & 3; t = 1;
            j = l ? (tot - 1) : (c0 - 1); // self-loop row = center node
        }
        const float4* r4 = (const float4*)(s_rows + j * RS) + kk * 16;
        const float4* w4 = (const float4*)(s_wv + ((l * 3 + t) * Hh + h) * RS) + kk * 16;
        float acc = 0.f;
        #pragma unroll
        for (int k = 0; k < 16; ++k) {
            float4 a = r4[k], w = w4[k];
            acc += a.x * w.x + a.y * w.y + a.z * w.z + a.w * w.w;
        }
        if (t0 < tot * 8) {
            if (t0 & 1) s_pm[(j * Hh + h) * 2 + kk] = acc;
            else        s_ps[(j * Hh + h) * 2 + kk] = acc;
        } else {
            s_pd[((l << 2) | h) * 2 + kk] = acc;
        }
    }
    __syncthreads();                                        // S5

    // ---- wave-parallel softmax: wave w=(l,h), lanes parallel over j ------
    {
        const int w = tid >> 6, lane = tid & 63;
        const int l = w >> 2, h = w & 3;
        const int j0 = l ? c0 : 0;
        const int cntl = (l ? tot : c0) - j0;     // <= MAXJ <= 64 lanes
        const float pd = s_pd[w * 2] + s_pd[w * 2 + 1];
        const bool valid = lane < cntl;
        const int j = j0 + (valid ? lane : 0);
        float e = valid ? (s_ps[(j * Hh + h) * 2] + s_ps[(j * Hh + h) * 2 + 1] + pd)
                        : -1e30f;
        e = (e >= 0.f) ? e : 0.2f * e;            // leaky relu, slope 0.2
        float m = e;
        #pragma unroll
        for (int off = 32; off > 0; off >>= 1)
            m = fmaxf(m, __shfl_xor(m, off));
        float ex = valid ? expf(e - m) : 0.f;
        float pm = valid ? (s_pm[(j * Hh + h) * 2] + s_pm[(j * Hh + h) * 2 + 1]) : 0.f;
        float den = ex, num = ex * pm;
        #pragma unroll
        for (int off = 32; off > 0; off >>= 1) {
            den += __shfl_xor(den, off);
            num += __shfl_xor(num, off);
        }
        if (lane == 0) s_hval[w] = num / den;
    }
    __syncthreads();                                        // S6

    if (tid == 0) {
        float r = 0.25f * (s_hval[0] + s_hval[1] + s_hval[2] + s_hval[3]) + s_bdot[0]
                + 0.25f * (s_hval[4] + s_hval[5] + s_hval[6] + s_hval[7]) + s_bdot[1];
        if (f32) ((float*)out)[b] = r;
        else     ((__hip_bfloat16*)out)[b] = __float2bfloat16(r);
    }
}

extern "C" void kernel_launch(void* const* d_in, const int* in_sizes, int n_in,
                              void* d_out, int out_size, void* d_ws, size_t ws_size,
                              hipStream_t stream) {
    const int* nn1  = (const int*)d_in[0];
    const int* nn2  = (const int*)d_in[1];
    const int* adj1 = (const int*)d_in[2];
    const int* adj2 = (const int*)d_in[3];
    float* wv = (float*)d_ws;     // 3074 fp32, fully rewritten every launch

    // dtype from host-side byte sizes (W1 = 512x128 elems); -1 -> device probe
    int sz5 = (in_sizes && n_in > 5) ? in_sizes[5] : 0;
    int f32arg = (sz5 == 512 * 128 * 4) ? 1 : ((sz5 == 512 * 128 * 2) ? 0 : -1);

    precompute_kernel<<<8, 256, 0, stream>>>(
        d_in[5],  /* W1  */ d_in[6],  /* as1 */ d_in[7],  /* ad1 */
        d_in[8],  /* b1  */
        d_in[9],  /* W2  */ d_in[10], /* as2 */ d_in[11], /* ad2 */
        d_in[12], /* b2  */
        d_in[13], /* mlpw */ d_in[14], /* mlpb */ wv);

    gat_main_kernel<<<Bg, 512, 0, stream>>>(
        nn1, nn2, adj1, adj2, d_in[4] /* emb */, d_in[5] /* W1 */, wv,
        f32arg, d_out);
}